// Round 8
// baseline (406.605 us; speedup 1.0000x reference)
//
#include <hip/hip_runtime.h>
#include <hip/hip_bf16.h>
#include <math.h>

// =============================================================================
// v16: v15 with conv1 moved to NBLK=128 (NTW=2).
// v15 evidence: VGPR=88 = exactly acc(24)+2x(Bv8+A24) for NTW=2 -> the
// sched_barrier-walled 2-deep pipeline HELD for conv2-5 (rest 344->298us),
// but conv1's NTW=4 needs 128+ regs and the allocator spilled/serialized
// inside the walls (70->98us, occupancy 21%).  Fix: conv1 joins the NTW=2
// regime (NBLK=128, grid Bc*32, LDS 21.3KB).  No other changes.
// =============================================================================

typedef __attribute__((ext_vector_type(8))) _Float16 f16x8;  // 8 fp16 in 4 VGPRs
typedef __attribute__((ext_vector_type(4))) float f32x4;

__device__ __forceinline__ unsigned short f2h_bits(float f) {
    union { _Float16 h; unsigned short u; } cv;
    cv.h = (_Float16)f;                      // v_cvt_f16_f32, RNE
    return cv.u;
}

// ---------------------------------------------------------------------------
// A image (per K-step of 32): [step][half(hi/lo)][mt(6)][lane(64)][j(8)] fp16,
// kg = s*32 + (lane>>4)*8 + j, ci = kg/KEFF, k = kg%KEFF (zero weight for
// k >= KW or kg >= CI*KEFF).  Wave mg reads segments {mg*3..mg*3+2}, both halves.
// B LDS image: CI rows of RD dwords; dword d of row ci = input elements
// (2*(t0+d), 2*(t0+d)+1), fp16-pair packed.  Fragment dword p for quad q at
// step s: g = 32s+8q+2p -> row g/KEFF, dword col wc0+l16+(g%KEFF)/2+nt*16.
// KEFF even => pair never straddles a row.  Offsets periodic in s with period
// PH = lcm(32,KEFF)/32 (10->5, 6->3, 8->1): offb[PH][4] base regs, the rest
// folds into ds_read offset: immediates ((s/PH)*PERRD + nt*16, max <64KB).
// K-loop: 2-deep register pipeline enforced by sched_barrier(0) walls; loads
// for step s+1 (alternate register set) emitted above step s's MFMA cluster.
// ---------------------------------------------------------------------------
template<int KEFF, int CI, int NBLK, bool IN_FP32, bool RELU, bool OUT_F16, bool POOL>
__global__ __launch_bounds__(512, 2)
void conv_nb(const unsigned short* __restrict__ xh,
             const unsigned short* __restrict__ wpk,
             const float* __restrict__ bias,
             unsigned short* __restrict__ yh,
             float* __restrict__ yf,
             int Tin, int Tout)
{
    constexpr int CO    = 96;
    constexpr int NTHR  = 512;
    constexpr int GTOT  = CI * KEFF;                // 400 / 576
    constexpr int STEPS = (GTOT + 31) / 32;         // 13 / 18
    constexpr int RD    = NBLK + KEFF / 2;          // dword cols per row
    constexpr int NTW   = NBLK / 64;                // 16-col fragments per wave
    constexpr int TOT   = CI * RD;                  // whole-tile dwords
    constexpr int NIT   = (TOT + NTHR - 1) / NTHR;
    constexpr int PH    = (32 % KEFF == 0) ? 1 : (((32 * 3) % KEFF == 0) ? 3 : 5);
    constexpr int PERRD = (32 * PH / KEFF) * RD;    // dwords per period

    __shared__ unsigned int Bs[TOT];                // 21.3 / 50.3 / 25.7 KB

    const int tid  = threadIdx.x;
    const int lane = tid & 63;
    const int wave = tid >> 6;
    const int mg   = wave & 1;            // output-channel half (3 mt each)
    const int tg   = wave >> 1;           // t-quarter
    const int quad = lane >> 4;
    const int l16  = lane & 15;
    const int wc0  = tg * (NBLK / 4);

    const int nT = (Tout + NBLK - 1) / NBLK;
    const int b  = blockIdx.x / nT;
    const int t0 = (blockIdx.x % nT) * NBLK;

    const float* xf = (const float*)xh;
    const unsigned int* xb = (const unsigned int*)xh + (((size_t)b * CI * Tin) >> 1);
    const int rowd = Tin >> 1;

    // ---- stage entire B tile (once); all edge reads clamped ----
    #pragma unroll
    for (int it = 0; it < NIT; ++it) {
        int i = tid + it * NTHR;
        if (i < TOT) {
            int r = (unsigned)i / (unsigned)RD, d = i - r * RD;
            unsigned int v;
            if (IN_FP32) {
                int e = 2 * (t0 + d);
                if (e > Tin - 2) e = Tin - 2;        // clamp: discarded cols only
                const float* src = xf + ((size_t)b * CI + r) * Tin + e;
                float2 w = *(const float2*)src;
                v = (unsigned int)f2h_bits(w.x) | ((unsigned int)f2h_bits(w.y) << 16);
            } else {
                int dd = t0 + d;
                if (dd > rowd - 1) dd = rowd - 1;    // clamp: zero-weight taps only
                v = *(xb + (size_t)r * rowd + dd);
            }
            Bs[i] = v;
        }
    }
    __syncthreads();

    // ---- per-phase B base offsets (immediates do the rest) ----
    int offb[PH][4];
    #pragma unroll
    for (int ph = 0; ph < PH; ++ph)
        #pragma unroll
        for (int p = 0; p < 4; ++p) {
            int g = 32 * ph + quad * 8 + 2 * p;
            unsigned ci = (unsigned)g / (unsigned)KEFF;
            unsigned dwo = ((unsigned)g - ci * (unsigned)KEFF) >> 1;
            offb[ph][p] = (int)ci * RD + wc0 + l16 + (int)dwo;
        }

    f32x4 acc[3][NTW];
    #pragma unroll
    for (int mt = 0; mt < 3; ++mt)
        #pragma unroll
        for (int nt = 0; nt < NTW; ++nt) acc[mt][nt] = (f32x4)0.f;

    union BvU { unsigned int u[4]; f16x8 v; };

    auto load_step = [&](int s, BvU (&Bv)[NTW], f16x8 (&Ah)[3], f16x8 (&Al)[3]) {
        if (32 * (s + 1) <= GTOT) {
            #pragma unroll
            for (int nt = 0; nt < NTW; ++nt)
                #pragma unroll
                for (int p = 0; p < 4; ++p)
                    Bv[nt].u[p] = Bs[offb[s % PH][p] + (s / PH) * PERRD + nt * 16];
        } else {
            // tail half-step (conv1 only): clamp to GTOT-2 (zero weights there)
            #pragma unroll
            for (int nt = 0; nt < NTW; ++nt)
                #pragma unroll
                for (int p = 0; p < 4; ++p) {
                    int g = 32 * s + quad * 8 + 2 * p;
                    if (g > GTOT - 2) g = GTOT - 2;
                    unsigned ci = (unsigned)g / (unsigned)KEFF;
                    unsigned dwo = ((unsigned)g - ci * (unsigned)KEFF) >> 1;
                    Bv[nt].u[p] = Bs[(int)ci * RD + wc0 + l16 + (int)dwo + nt * 16];
                }
        }
        const unsigned short* ap = wpk + (size_t)s * 6144 + (size_t)(mg * 3) * 512
                                 + (size_t)lane * 8;
        #pragma unroll
        for (int mt = 0; mt < 3; ++mt) {
            Ah[mt] = *(const f16x8*)(ap + mt * 512);          // L1/L2-hot
            Al[mt] = *(const f16x8*)(ap + 3072 + mt * 512);
        }
    };
    auto mfma_step = [&](BvU (&Bv)[NTW], f16x8 (&Ah)[3], f16x8 (&Al)[3]) {
        #pragma unroll
        for (int mt = 0; mt < 3; ++mt)
            #pragma unroll
            for (int nt = 0; nt < NTW; ++nt)
                acc[mt][nt] = __builtin_amdgcn_mfma_f32_16x16x32_f16(Ah[mt], Bv[nt].v, acc[mt][nt], 0, 0, 0);
        #pragma unroll
        for (int mt = 0; mt < 3; ++mt)
            #pragma unroll
            for (int nt = 0; nt < NTW; ++nt)
                acc[mt][nt] = __builtin_amdgcn_mfma_f32_16x16x32_f16(Al[mt], Bv[nt].v, acc[mt][nt], 0, 0, 0);
    };

    // ---- barrier-free K loop, forced 2-deep pipeline ----
    BvU  Bv0[NTW], Bv1[NTW];
    f16x8 Ah0[3], Al0[3], Ah1[3], Al1[3];

    load_step(0, Bv0, Ah0, Al0);
    #pragma unroll
    for (int s = 0; s < STEPS; ++s) {
        if (s + 1 < STEPS) {
            if (((s + 1) & 1) == 0) load_step(s + 1, Bv0, Ah0, Al0);
            else                    load_step(s + 1, Bv1, Ah1, Al1);
        }
        __builtin_amdgcn_sched_barrier(0);   // loads stay ABOVE the MFMA cluster
        __builtin_amdgcn_s_setprio(1);
        if ((s & 1) == 0) mfma_step(Bv0, Ah0, Al0);
        else              mfma_step(Bv1, Ah1, Al1);
        __builtin_amdgcn_s_setprio(0);
        __builtin_amdgcn_sched_barrier(0);   // and nothing leaks into it
    }

    // epilogue: C/D layout col=l16 (t), row = quad*4+reg
    #pragma unroll
    for (int mt = 0; mt < 3; ++mt) {
        #pragma unroll
        for (int r = 0; r < 4; ++r) {
            int o = (mg * 3 + mt) * 16 + quad * 4 + r;
            float bv = bias[o];
            #pragma unroll
            for (int nt = 0; nt < NTW; ++nt) {
                int t = t0 + wc0 + nt * 16 + l16;
                float v = acc[mt][nt][r] + bv;
                if (RELU) v = fmaxf(v, 0.f);
                if (POOL) {
                    float sum = v + __shfl_xor(v, 1, 64);
                    if ((lane & 1) == 0 && t + 1 < Tout) {
                        float pr = fmaxf(0.5f * sum, 0.f);
                        size_t pidx = ((size_t)b * CO + o) * (Tout >> 1) + (t >> 1);
                        if (OUT_F16) yh[pidx] = f2h_bits(pr);
                        else         yf[pidx] = pr;
                    }
                } else if (OUT_F16) {
                    // packed dword store: lanes (t, t+1) pair via shfl (t0 even)
                    unsigned int h = f2h_bits(v);
                    unsigned int hp = (unsigned int)__shfl_xor((int)h, 1, 64);
                    if ((lane & 1) == 0 && t + 1 < Tout) {
                        size_t base = ((size_t)b * CO + o) * Tout + t;   // even
                        *(unsigned int*)(yh + base) = h | (hp << 16);
                    }
                } else if (t < Tout) {
                    yf[((size_t)b * CO + o) * Tout + t] = v;
                }
            }
        }
    }
}

// ---------------------------------------------------------------------------
// single repack kernel: 5 MFMA A-images (fp16 hi/lo) + 2 fp32 [ci][k][o]
// conv1: KEFF=10 (13 steps, 79872); conv2-5: KEFF=6 (18 steps, 110592 each)
// ---------------------------------------------------------------------------
__device__ __forceinline__ void repack_img(const float* __restrict__ w,
                                           unsigned short* __restrict__ wpk,
                                           int idx, int KP, int KW, int CI)
{
    int j = idx & 7, lane = (idx >> 3) & 63, g = idx >> 9;
    int c = g / 24, r = g % 24;
    int mt = r % 6, sh = r / 6;
    int half = sh & 1, s = sh >> 1;
    int S  = c * 2 + s;
    int kg = S * 32 + (lane >> 4) * 8 + j;
    int o  = mt * 16 + (lane & 15);
    int ci = kg / KP, k = kg - ci * KP;
    float val = (ci < CI && k < KW) ? w[((size_t)o * CI + ci) * KW + k] : 0.f;
    _Float16 hh = (_Float16)val;
    union { _Float16 h; unsigned short u; } cv;
    cv.h = (half == 0) ? hh : (_Float16)(val - (float)hh);
    wpk[idx] = cv.u;
}
__device__ __forceinline__ void repack_okc(const float* __restrict__ w,
                                           float* __restrict__ wr,
                                           int idx, int CI, int K, int CO)
{
    int o = idx % CO; int rem = idx / CO; int k = rem % K; int ci = rem / K;
    wr[idx] = w[((size_t)o * CI + ci) * K + k];
}

__global__ void repack_all(const float* w1, const float* w2, const float* w3,
                           const float* w4, const float* w5, const float* w6,
                           const float* w7,
                           unsigned short* p1, unsigned short* p2,
                           unsigned short* p3, unsigned short* p4,
                           unsigned short* p5, float* r6, float* r7)
{
    int idx = blockIdx.x * 256 + threadIdx.x;
    if (idx < 79872)  { repack_img(w1, p1, idx, 10, 10, 40); return; }  // 13 steps
    idx -= 79872;
    if (idx < 110592) { repack_img(w2, p2, idx, 6, 5, 96); return; }    // 18 steps
    idx -= 110592;
    if (idx < 110592) { repack_img(w3, p3, idx, 6, 5, 96); return; }
    idx -= 110592;
    if (idx < 110592) { repack_img(w4, p4, idx, 6, 5, 96); return; }
    idx -= 110592;
    if (idx < 110592) { repack_img(w5, p5, idx, 6, 5, 96); return; }
    idx -= 110592;
    if (idx < 46080)  { repack_okc(w6, r6, idx, 96, 5, 96); return; }
    idx -= 46080;
    if (idx < 36864)  { repack_okc(w7, r7, idx, 96, 3, 128); return; }
}

// ---------------------------------------------------------------------------
// conv6: 96->96, K=5, s=2, 62->29, relu.  Grid 256 = 64 samples x 4 o-blocks.
// ---------------------------------------------------------------------------
__global__ __launch_bounds__(256)
void conv6_k(const float* __restrict__ y5p, const float* __restrict__ w6r,
             const float* __restrict__ b6, float* __restrict__ y6)
{
    __shared__ float s5[96 * 62];
    const int b = blockIdx.x >> 2, ob = blockIdx.x & 3;
    const int tid = threadIdx.x;
    for (int i = tid; i < 96 * 62; i += 256) s5[i] = y5p[(size_t)b * 96 * 62 + i];
    __syncthreads();

    const int wave = __builtin_amdgcn_readfirstlane(tid >> 6);
    const int t = tid & 63;
    if (t < 29) {
        const int o0 = ob * 24 + wave * 6;
        float a[6];
        #pragma unroll
        for (int oo = 0; oo < 6; oo++) a[oo] = 0.f;
        for (int ci = 0; ci < 96; ci++) {
            float xr[5];
            #pragma unroll
            for (int k = 0; k < 5; k++) xr[k] = s5[ci * 62 + 2 * t + k];
            #pragma unroll
            for (int k = 0; k < 5; k++) {
                const float* wp = w6r + (ci * 5 + k) * 96 + o0;   // wave-uniform
                #pragma unroll
                for (int oo = 0; oo < 6; oo++)
                    a[oo] = fmaf(wp[oo], xr[k], a[oo]);
            }
        }
        #pragma unroll
        for (int oo = 0; oo < 6; oo++)
            y6[((size_t)b * 96 + o0 + oo) * 29 + t] = fmaxf(a[oo] + b6[o0 + oo], 0.f);
    }
}

// ---------------------------------------------------------------------------
// tail2: conv7 (96->128, K=3, s=2, 29->14, relu) + masked max + MLP head.
// ---------------------------------------------------------------------------
__global__ __launch_bounds__(256)
void tail2(const float* __restrict__ y6,
           const float* __restrict__ w7r, const float* __restrict__ b7,
           const int* __restrict__ lens,
           const float* __restrict__ lw1, const float* __restrict__ lb1,
           const float* __restrict__ lw2, const float* __restrict__ lb2,
           const float* __restrict__ lw3, const float* __restrict__ lb3,
           float* __restrict__ out)
{
    __shared__ float s6[96 * 29 + 8];     // +8: benign overread slack (tl>=14)
    __shared__ float s7[128 * 14];
    __shared__ float feat[128], h1[128], h2[64];

    const int b = blockIdx.x, tid = threadIdx.x;
    for (int i = tid; i < 96 * 29; i += 256) s6[i] = y6[(size_t)b * 96 * 29 + i];
    __syncthreads();

    const int wave = __builtin_amdgcn_readfirstlane(tid >> 6);
    const int lane = tid & 63;
    const int sub  = lane >> 4;           // ci quarter
    const int tl   = lane & 15;           // t (active tl<14)
    {
        float a[32];
        #pragma unroll
        for (int oo = 0; oo < 32; oo++) a[oo] = 0.f;
        const int ci0 = sub * 24;
        for (int ci = ci0; ci < ci0 + 24; ci++) {
            float xr[3];
            #pragma unroll
            for (int k = 0; k < 3; k++) xr[k] = s6[ci * 29 + 2 * tl + k];
            #pragma unroll
            for (int k = 0; k < 3; k++) {
                const float* wp = w7r + (ci * 3 + k) * 128 + wave * 32;  // uniform
                #pragma unroll
                for (int oo = 0; oo < 32; oo++)
                    a[oo] = fmaf(wp[oo], xr[k], a[oo]);
            }
        }
        #pragma unroll
        for (int oo = 0; oo < 32; oo++) {
            float v = a[oo];
            v += __shfl_xor(v, 16, 64);   // sub 0<->1, 2<->3 (same tl)
            v += __shfl_xor(v, 32, 64);   // sub 0<->2
            if (sub == 0 && tl < 14) {
                int o = wave * 32 + oo;
                s7[o * 14 + tl] = fmaxf(v + b7[o], 0.f);
            }
        }
    }
    __syncthreads();

    if (tid < 128) {
        int L = lens[b];
        L = (L - 10) / 2 + 1;
        L = (L - 5) / 2 + 1;
        L = (L - 5) / 2 + 1;
        L = (L - 5) / 2 + 1;
        L = L / 2;
        L = (L - 5) / 2 + 1;
        L = L / 2;
        L = (L - 5) / 2 + 1;
        L = (L - 3) / 2 + 1;
        float m = -INFINITY;
        for (int t = 0; t < L; t++) m = fmaxf(m, s7[tid * 14 + t]);
        feat[tid] = m;
    }
    __syncthreads();

    if (tid < 128) {
        float s = lb1[tid];
        for (int i = 0; i < 128; i++) s = fmaf(lw1[tid * 128 + i], feat[i], s);
        h1[tid] = fmaxf(s, 0.f);
    }
    __syncthreads();
    if (tid < 64) {
        float s = lb2[tid];
        for (int i = 0; i < 128; i++) s = fmaf(lw2[tid * 128 + i], h1[i], s);
        h2[tid] = fmaxf(s, 0.f);
    }
    __syncthreads();
    if (tid < 5) {
        float s = lb3[tid];
        for (int i = 0; i < 64; i++) s = fmaf(lw3[tid * 64 + i], h2[i], s);
        out[b * 5 + tid] = s;
    }
}

extern "C" void kernel_launch(void* const* d_in, const int* in_sizes, int n_in,
                              void* d_out, int out_size, void* d_ws, size_t ws_size,
                              hipStream_t stream)
{
    const float* x    = (const float*)d_in[0];
    const int*   lens = (const int*)  d_in[1];
    const float* w1 = (const float*)d_in[2];   const float* b1 = (const float*)d_in[3];
    const float* w2 = (const float*)d_in[4];   const float* b2 = (const float*)d_in[5];
    const float* w3 = (const float*)d_in[6];   const float* b3 = (const float*)d_in[7];
    const float* w4 = (const float*)d_in[8];   const float* b4 = (const float*)d_in[9];
    const float* w5 = (const float*)d_in[10];  const float* b5 = (const float*)d_in[11];
    const float* w6 = (const float*)d_in[12];  const float* b6 = (const float*)d_in[13];
    const float* w7 = (const float*)d_in[14];  const float* b7 = (const float*)d_in[15];
    const float* lw1 = (const float*)d_in[16]; const float* lb1 = (const float*)d_in[17];
    const float* lw2 = (const float*)d_in[18]; const float* lb2 = (const float*)d_in[19];
    const float* lw3 = (const float*)d_in[20]; const float* lb3 = (const float*)d_in[21];
    float* out = (float*)d_out;
    char*  W   = (char*)d_ws;

    // lengths: 8192 -> 4092 -> 2044 -> 1020 -> 508 -> 254 -> 125 -> 62 -> 29 -> 14
    size_t off = 0;
    auto take = [&](size_t bytes) {
        size_t o = off; off = (off + bytes + 255) & ~(size_t)255; return o;
    };
    size_t o_y3h = take(((size_t)64 * 96 * 1020 + 2048) * 2);
    size_t o_y4h = take(((size_t)64 * 96 * 254 + 2048) * 2);   // fp16 pooled
    size_t o_y5p = take((size_t)64 * 96 * 62 * 4 + 1024);      // fp32 pooled
    size_t o_y6  = take((size_t)64 * 96 * 29 * 4);
    size_t o_wp1 = take((size_t)79872 * 2);    // 13 steps x 6144
    size_t o_wp2 = take((size_t)110592 * 2);   // 18 steps x 6144
    size_t o_wp3 = take((size_t)110592 * 2);
    size_t o_wp4 = take((size_t)110592 * 2);
    size_t o_wp5 = take((size_t)110592 * 2);
    size_t o_w6r = take((size_t)46080 * 4);
    size_t o_w7r = take((size_t)36864 * 4);
    size_t persist = off;

    auto chunk_bytes = [&](int Bc) -> size_t {
        size_t s = 0;
        s += ((size_t)Bc * 96 * 4092 + 2048) * 2 + 256;
        s += ((size_t)Bc * 96 * 2044 + 2048) * 2 + 256;
        return s;
    };
    int Bc = 64;
    while (Bc > 1 && persist + chunk_bytes(Bc) > ws_size) Bc >>= 1;
    size_t o_y1h = take(((size_t)Bc * 96 * 4092 + 2048) * 2);
    size_t o_y2h = take(((size_t)Bc * 96 * 2044 + 2048) * 2);

    auto US = [&](size_t o) { return (unsigned short*)(W + o); };
    auto FP = [&](size_t o) { return (float*)(W + o); };

    // one repack kernel (605184 elements)
    repack_all<<<dim3((605184 + 255) / 256), 256, 0, stream>>>(
        w1, w2, w3, w4, w5, w6, w7,
        US(o_wp1), US(o_wp2), US(o_wp3), US(o_wp4), US(o_wp5),
        FP(o_w6r), FP(o_w7r));

    const int nchunks = 64 / Bc;
    for (int c = 0; c < nchunks; c++) {
        const float* xc = x + (size_t)c * Bc * 40 * 8192;

        // conv1: fp32 in (fused convert), KEFF=10, NBLK=128 -> nT=32, LDS 21.3KB
        conv_nb<10, 40, 128, true, true, true, false><<<dim3(Bc * 32), 512, 0, stream>>>(
            (const unsigned short*)xc, US(o_wp1), b1, US(o_y1h), nullptr, 8192, 4092);
        // conv2: KEFF=6, NBLK=128 -> nT=16, LDS 50.3KB
        conv_nb< 6, 96, 128, false, true, true, false><<<dim3(Bc * 16), 512, 0, stream>>>(
            US(o_y1h), US(o_wp2), b2, US(o_y2h), nullptr, 4092, 2044);
        // conv3: KEFF=6, NBLK=128 -> nT=8
        unsigned short* y3h_c = US(o_y3h) + (size_t)c * Bc * 96 * 1020;
        conv_nb< 6, 96, 128, false, true, true, false><<<dim3(Bc * 8), 512, 0, stream>>>(
            US(o_y2h), US(o_wp3), b3, y3h_c, nullptr, 2044, 1020);
    }

    // conv4: NBLK=64 -> nT=8 (grid 512); fused AvgPool2+ReLU -> y4h (fp16, T=254)
    conv_nb<6, 96, 64, false, false, true, true><<<dim3(64 * 8), 512, 0, stream>>>(
        US(o_y3h), US(o_wp4), b4, US(o_y4h), nullptr, 1020, 508);

    // conv5 (MFMA): NBLK=64 -> nT=2; fused AvgPool2+ReLU -> y5p (fp32, T=62)
    conv_nb<6, 96, 64, false, false, false, true><<<dim3(64 * 2), 512, 0, stream>>>(
        US(o_y4h), US(o_wp5), b5, nullptr, FP(o_y5p), 254, 125);

    // conv6: grid 256 (64 samples x 4 o-blocks)
    conv6_k<<<dim3(256), 256, 0, stream>>>(FP(o_y5p), FP(o_w6r), b6, FP(o_y6));

    // conv7 + masked max + MLP head
    tail2<<<dim3(64), 256, 0, stream>>>(
        FP(o_y6), FP(o_w7r), b7, lens, lw1, lb1, lw2, lb2, lw3, lb3, out);
}

// Round 9
// 378.720 us; speedup vs baseline: 1.0736x; 1.0736x over previous
//
#include <hip/hip_runtime.h>
#include <hip/hip_bf16.h>
#include <math.h>

// =============================================================================
// v17: per-conv recombination of measured winners.
//  - conv1: v14-exact structure (PIPE=0): simple per-step loop, NO sched
//    walls, NBLK=256 (NTW=4), KEFF=10 periodic immediate offsets.  Measured
//    70us in v14; walls versions (v15/v16) were 95-98us because the 2-deep
//    register set never fit (VGPR 68-88 < needed) and the walls forbade the
//    scheduler from compensating.
//  - conv2-5: v15-exact walls pipeline (PIPE=1): 2-deep named register sets
//    + sched_barrier(0) walls + setprio around MFMA.  Measured best (rest
//    ~298us) - at NTW<=2 geometry the pipeline fits (VGPR=88) and holds.
//  - packed fp16 dword epilogue stores kept everywhere.
// Numerics identical throughout (same products, same order).
// =============================================================================

typedef __attribute__((ext_vector_type(8))) _Float16 f16x8;  // 8 fp16 in 4 VGPRs
typedef __attribute__((ext_vector_type(4))) float f32x4;

__device__ __forceinline__ unsigned short f2h_bits(float f) {
    union { _Float16 h; unsigned short u; } cv;
    cv.h = (_Float16)f;                      // v_cvt_f16_f32, RNE
    return cv.u;
}

// ---------------------------------------------------------------------------
// A image (per K-step of 32): [step][half(hi/lo)][mt(6)][lane(64)][j(8)] fp16,
// kg = s*32 + (lane>>4)*8 + j, ci = kg/KEFF, k = kg%KEFF (zero weight for
// k >= KW or kg >= CI*KEFF).  Wave mg reads segments {mg*3..mg*3+2}, both halves.
// B LDS image: CI rows of RD dwords; dword d of row ci = input elements
// (2*(t0+d), 2*(t0+d)+1), fp16-pair packed.  Fragment dword p for quad q at
// step s: g = 32s+8q+2p -> row g/KEFF, dword col wc0+l16+(g%KEFF)/2+nt*16.
// KEFF even => pair never straddles a row.  Offsets periodic in s with period
// PH = lcm(32,KEFF)/32 (10->5, 6->3): offb[PH][4] base regs, the rest folds
// into ds_read offset: immediates ((s/PH)*PERRD + nt*16, max <64KB).
// PIPE=0: simple per-step load+mfma (compiler schedules freely).
// PIPE=1: 2-deep register pipeline enforced by sched_barrier(0) walls.
// ---------------------------------------------------------------------------
template<int KEFF, int CI, int NBLK, bool IN_FP32, bool RELU, bool OUT_F16,
         bool POOL, int PIPE>
__global__ __launch_bounds__(512, 2)
void conv_nb(const unsigned short* __restrict__ xh,
             const unsigned short* __restrict__ wpk,
             const float* __restrict__ bias,
             unsigned short* __restrict__ yh,
             float* __restrict__ yf,
             int Tin, int Tout)
{
    constexpr int CO    = 96;
    constexpr int NTHR  = 512;
    constexpr int GTOT  = CI * KEFF;                // 400 / 576
    constexpr int STEPS = (GTOT + 31) / 32;         // 13 / 18
    constexpr int RD    = NBLK + KEFF / 2;          // dword cols per row
    constexpr int NTW   = NBLK / 64;                // 16-col fragments per wave
    constexpr int TOT   = CI * RD;                  // whole-tile dwords
    constexpr int NIT   = (TOT + NTHR - 1) / NTHR;
    constexpr int PH    = (32 % KEFF == 0) ? 1 : (((32 * 3) % KEFF == 0) ? 3 : 5);
    constexpr int PERRD = (32 * PH / KEFF) * RD;    // dwords per period

    __shared__ unsigned int Bs[TOT];                // 41.8 / 50.3 / 25.7 KB

    const int tid  = threadIdx.x;
    const int lane = tid & 63;
    const int wave = tid >> 6;
    const int mg   = wave & 1;            // output-channel half (3 mt each)
    const int tg   = wave >> 1;           // t-quarter
    const int quad = lane >> 4;
    const int l16  = lane & 15;
    const int wc0  = tg * (NBLK / 4);

    const int nT = (Tout + NBLK - 1) / NBLK;
    const int b  = blockIdx.x / nT;
    const int t0 = (blockIdx.x % nT) * NBLK;

    const float* xf = (const float*)xh;
    const unsigned int* xb = (const unsigned int*)xh + (((size_t)b * CI * Tin) >> 1);
    const int rowd = Tin >> 1;

    // ---- stage entire B tile (once); all edge reads clamped ----
    #pragma unroll
    for (int it = 0; it < NIT; ++it) {
        int i = tid + it * NTHR;
        if (i < TOT) {
            int r = (unsigned)i / (unsigned)RD, d = i - r * RD;
            unsigned int v;
            if (IN_FP32) {
                int e = 2 * (t0 + d);
                if (e > Tin - 2) e = Tin - 2;        // clamp: discarded cols only
                const float* src = xf + ((size_t)b * CI + r) * Tin + e;
                float2 w = *(const float2*)src;
                v = (unsigned int)f2h_bits(w.x) | ((unsigned int)f2h_bits(w.y) << 16);
            } else {
                int dd = t0 + d;
                if (dd > rowd - 1) dd = rowd - 1;    // clamp: zero-weight taps only
                v = *(xb + (size_t)r * rowd + dd);
            }
            Bs[i] = v;
        }
    }
    __syncthreads();

    // ---- per-phase B base offsets (immediates do the rest) ----
    int offb[PH][4];
    #pragma unroll
    for (int ph = 0; ph < PH; ++ph)
        #pragma unroll
        for (int p = 0; p < 4; ++p) {
            int g = 32 * ph + quad * 8 + 2 * p;
            unsigned ci = (unsigned)g / (unsigned)KEFF;
            unsigned dwo = ((unsigned)g - ci * (unsigned)KEFF) >> 1;
            offb[ph][p] = (int)ci * RD + wc0 + l16 + (int)dwo;
        }

    f32x4 acc[3][NTW];
    #pragma unroll
    for (int mt = 0; mt < 3; ++mt)
        #pragma unroll
        for (int nt = 0; nt < NTW; ++nt) acc[mt][nt] = (f32x4)0.f;

    union BvU { unsigned int u[4]; f16x8 v; };

    auto load_step = [&](int s, BvU (&Bv)[NTW], f16x8 (&Ah)[3], f16x8 (&Al)[3]) {
        if (32 * (s + 1) <= GTOT) {
            #pragma unroll
            for (int nt = 0; nt < NTW; ++nt)
                #pragma unroll
                for (int p = 0; p < 4; ++p)
                    Bv[nt].u[p] = Bs[offb[s % PH][p] + (s / PH) * PERRD + nt * 16];
        } else {
            // tail half-step (conv1 only): clamp to GTOT-2 (zero weights there)
            #pragma unroll
            for (int nt = 0; nt < NTW; ++nt)
                #pragma unroll
                for (int p = 0; p < 4; ++p) {
                    int g = 32 * s + quad * 8 + 2 * p;
                    if (g > GTOT - 2) g = GTOT - 2;
                    unsigned ci = (unsigned)g / (unsigned)KEFF;
                    unsigned dwo = ((unsigned)g - ci * (unsigned)KEFF) >> 1;
                    Bv[nt].u[p] = Bs[(int)ci * RD + wc0 + l16 + (int)dwo + nt * 16];
                }
        }
        const unsigned short* ap = wpk + (size_t)s * 6144 + (size_t)(mg * 3) * 512
                                 + (size_t)lane * 8;
        #pragma unroll
        for (int mt = 0; mt < 3; ++mt) {
            Ah[mt] = *(const f16x8*)(ap + mt * 512);          // L1/L2-hot
            Al[mt] = *(const f16x8*)(ap + 3072 + mt * 512);
        }
    };
    auto mfma_step = [&](BvU (&Bv)[NTW], f16x8 (&Ah)[3], f16x8 (&Al)[3]) {
        #pragma unroll
        for (int mt = 0; mt < 3; ++mt)
            #pragma unroll
            for (int nt = 0; nt < NTW; ++nt)
                acc[mt][nt] = __builtin_amdgcn_mfma_f32_16x16x32_f16(Ah[mt], Bv[nt].v, acc[mt][nt], 0, 0, 0);
        #pragma unroll
        for (int mt = 0; mt < 3; ++mt)
            #pragma unroll
            for (int nt = 0; nt < NTW; ++nt)
                acc[mt][nt] = __builtin_amdgcn_mfma_f32_16x16x32_f16(Al[mt], Bv[nt].v, acc[mt][nt], 0, 0, 0);
    };

    if (PIPE == 0) {
        // ---- v14-style simple loop: compiler schedules freely ----
        #pragma unroll
        for (int s = 0; s < STEPS; ++s) {
            BvU Bv[NTW];
            f16x8 Ah[3], Al[3];
            load_step(s, Bv, Ah, Al);
            mfma_step(Bv, Ah, Al);
        }
    } else {
        // ---- walls-enforced 2-deep register pipeline ----
        BvU  Bv0[NTW], Bv1[NTW];
        f16x8 Ah0[3], Al0[3], Ah1[3], Al1[3];

        load_step(0, Bv0, Ah0, Al0);
        #pragma unroll
        for (int s = 0; s < STEPS; ++s) {
            if (s + 1 < STEPS) {
                if (((s + 1) & 1) == 0) load_step(s + 1, Bv0, Ah0, Al0);
                else                    load_step(s + 1, Bv1, Ah1, Al1);
            }
            __builtin_amdgcn_sched_barrier(0);   // loads stay ABOVE the MFMAs
            __builtin_amdgcn_s_setprio(1);
            if ((s & 1) == 0) mfma_step(Bv0, Ah0, Al0);
            else              mfma_step(Bv1, Ah1, Al1);
            __builtin_amdgcn_s_setprio(0);
            __builtin_amdgcn_sched_barrier(0);   // and nothing leaks into it
        }
    }

    // epilogue: C/D layout col=l16 (t), row = quad*4+reg
    #pragma unroll
    for (int mt = 0; mt < 3; ++mt) {
        #pragma unroll
        for (int r = 0; r < 4; ++r) {
            int o = (mg * 3 + mt) * 16 + quad * 4 + r;
            float bv = bias[o];
            #pragma unroll
            for (int nt = 0; nt < NTW; ++nt) {
                int t = t0 + wc0 + nt * 16 + l16;
                float v = acc[mt][nt][r] + bv;
                if (RELU) v = fmaxf(v, 0.f);
                if (POOL) {
                    float sum = v + __shfl_xor(v, 1, 64);
                    if ((lane & 1) == 0 && t + 1 < Tout) {
                        float pr = fmaxf(0.5f * sum, 0.f);
                        size_t pidx = ((size_t)b * CO + o) * (Tout >> 1) + (t >> 1);
                        if (OUT_F16) yh[pidx] = f2h_bits(pr);
                        else         yf[pidx] = pr;
                    }
                } else if (OUT_F16) {
                    // packed dword store: lanes (t, t+1) pair via shfl (t even)
                    unsigned int h = f2h_bits(v);
                    unsigned int hp = (unsigned int)__shfl_xor((int)h, 1, 64);
                    if ((lane & 1) == 0 && t + 1 < Tout) {
                        size_t base = ((size_t)b * CO + o) * Tout + t;   // even
                        *(unsigned int*)(yh + base) = h | (hp << 16);
                    }
                } else if (t < Tout) {
                    yf[((size_t)b * CO + o) * Tout + t] = v;
                }
            }
        }
    }
}

// ---------------------------------------------------------------------------
// single repack kernel: 5 MFMA A-images (fp16 hi/lo) + 2 fp32 [ci][k][o]
// conv1: KEFF=10 (13 steps, 79872); conv2-5: KEFF=6 (18 steps, 110592 each)
// ---------------------------------------------------------------------------
__device__ __forceinline__ void repack_img(const float* __restrict__ w,
                                           unsigned short* __restrict__ wpk,
                                           int idx, int KP, int KW, int CI)
{
    int j = idx & 7, lane = (idx >> 3) & 63, g = idx >> 9;
    int c = g / 24, r = g % 24;
    int mt = r % 6, sh = r / 6;
    int half = sh & 1, s = sh >> 1;
    int S  = c * 2 + s;
    int kg = S * 32 + (lane >> 4) * 8 + j;
    int o  = mt * 16 + (lane & 15);
    int ci = kg / KP, k = kg - ci * KP;
    float val = (ci < CI && k < KW) ? w[((size_t)o * CI + ci) * KW + k] : 0.f;
    _Float16 hh = (_Float16)val;
    union { _Float16 h; unsigned short u; } cv;
    cv.h = (half == 0) ? hh : (_Float16)(val - (float)hh);
    wpk[idx] = cv.u;
}
__device__ __forceinline__ void repack_okc(const float* __restrict__ w,
                                           float* __restrict__ wr,
                                           int idx, int CI, int K, int CO)
{
    int o = idx % CO; int rem = idx / CO; int k = rem % K; int ci = rem / K;
    wr[idx] = w[((size_t)o * CI + ci) * K + k];
}

__global__ void repack_all(const float* w1, const float* w2, const float* w3,
                           const float* w4, const float* w5, const float* w6,
                           const float* w7,
                           unsigned short* p1, unsigned short* p2,
                           unsigned short* p3, unsigned short* p4,
                           unsigned short* p5, float* r6, float* r7)
{
    int idx = blockIdx.x * 256 + threadIdx.x;
    if (idx < 79872)  { repack_img(w1, p1, idx, 10, 10, 40); return; }  // 13 steps
    idx -= 79872;
    if (idx < 110592) { repack_img(w2, p2, idx, 6, 5, 96); return; }    // 18 steps
    idx -= 110592;
    if (idx < 110592) { repack_img(w3, p3, idx, 6, 5, 96); return; }
    idx -= 110592;
    if (idx < 110592) { repack_img(w4, p4, idx, 6, 5, 96); return; }
    idx -= 110592;
    if (idx < 110592) { repack_img(w5, p5, idx, 6, 5, 96); return; }
    idx -= 110592;
    if (idx < 46080)  { repack_okc(w6, r6, idx, 96, 5, 96); return; }
    idx -= 46080;
    if (idx < 36864)  { repack_okc(w7, r7, idx, 96, 3, 128); return; }
}

// ---------------------------------------------------------------------------
// conv6: 96->96, K=5, s=2, 62->29, relu.  Grid 256 = 64 samples x 4 o-blocks.
// ---------------------------------------------------------------------------
__global__ __launch_bounds__(256)
void conv6_k(const float* __restrict__ y5p, const float* __restrict__ w6r,
             const float* __restrict__ b6, float* __restrict__ y6)
{
    __shared__ float s5[96 * 62];
    const int b = blockIdx.x >> 2, ob = blockIdx.x & 3;
    const int tid = threadIdx.x;
    for (int i = tid; i < 96 * 62; i += 256) s5[i] = y5p[(size_t)b * 96 * 62 + i];
    __syncthreads();

    const int wave = __builtin_amdgcn_readfirstlane(tid >> 6);
    const int t = tid & 63;
    if (t < 29) {
        const int o0 = ob * 24 + wave * 6;
        float a[6];
        #pragma unroll
        for (int oo = 0; oo < 6; oo++) a[oo] = 0.f;
        for (int ci = 0; ci < 96; ci++) {
            float xr[5];
            #pragma unroll
            for (int k = 0; k < 5; k++) xr[k] = s5[ci * 62 + 2 * t + k];
            #pragma unroll
            for (int k = 0; k < 5; k++) {
                const float* wp = w6r + (ci * 5 + k) * 96 + o0;   // wave-uniform
                #pragma unroll
                for (int oo = 0; oo < 6; oo++)
                    a[oo] = fmaf(wp[oo], xr[k], a[oo]);
            }
        }
        #pragma unroll
        for (int oo = 0; oo < 6; oo++)
            y6[((size_t)b * 96 + o0 + oo) * 29 + t] = fmaxf(a[oo] + b6[o0 + oo], 0.f);
    }
}

// ---------------------------------------------------------------------------
// tail2: conv7 (96->128, K=3, s=2, 29->14, relu) + masked max + MLP head.
// ---------------------------------------------------------------------------
__global__ __launch_bounds__(256)
void tail2(const float* __restrict__ y6,
           const float* __restrict__ w7r, const float* __restrict__ b7,
           const int* __restrict__ lens,
           const float* __restrict__ lw1, const float* __restrict__ lb1,
           const float* __restrict__ lw2, const float* __restrict__ lb2,
           const float* __restrict__ lw3, const float* __restrict__ lb3,
           float* __restrict__ out)
{
    __shared__ float s6[96 * 29 + 8];     // +8: benign overread slack (tl>=14)
    __shared__ float s7[128 * 14];
    __shared__ float feat[128], h1[128], h2[64];

    const int b = blockIdx.x, tid = threadIdx.x;
    for (int i = tid; i < 96 * 29; i += 256) s6[i] = y6[(size_t)b * 96 * 29 + i];
    __syncthreads();

    const int wave = __builtin_amdgcn_readfirstlane(tid >> 6);
    const int lane = tid & 63;
    const int sub  = lane >> 4;           // ci quarter
    const int tl   = lane & 15;           // t (active tl<14)
    {
        float a[32];
        #pragma unroll
        for (int oo = 0; oo < 32; oo++) a[oo] = 0.f;
        const int ci0 = sub * 24;
        for (int ci = ci0; ci < ci0 + 24; ci++) {
            float xr[3];
            #pragma unroll
            for (int k = 0; k < 3; k++) xr[k] = s6[ci * 29 + 2 * tl + k];
            #pragma unroll
            for (int k = 0; k < 3; k++) {
                const float* wp = w7r + (ci * 3 + k) * 128 + wave * 32;  // uniform
                #pragma unroll
                for (int oo = 0; oo < 32; oo++)
                    a[oo] = fmaf(wp[oo], xr[k], a[oo]);
            }
        }
        #pragma unroll
        for (int oo = 0; oo < 32; oo++) {
            float v = a[oo];
            v += __shfl_xor(v, 16, 64);   // sub 0<->1, 2<->3 (same tl)
            v += __shfl_xor(v, 32, 64);   // sub 0<->2
            if (sub == 0 && tl < 14) {
                int o = wave * 32 + oo;
                s7[o * 14 + tl] = fmaxf(v + b7[o], 0.f);
            }
        }
    }
    __syncthreads();

    if (tid < 128) {
        int L = lens[b];
        L = (L - 10) / 2 + 1;
        L = (L - 5) / 2 + 1;
        L = (L - 5) / 2 + 1;
        L = (L - 5) / 2 + 1;
        L = L / 2;
        L = (L - 5) / 2 + 1;
        L = L / 2;
        L = (L - 5) / 2 + 1;
        L = (L - 3) / 2 + 1;
        float m = -INFINITY;
        for (int t = 0; t < L; t++) m = fmaxf(m, s7[tid * 14 + t]);
        feat[tid] = m;
    }
    __syncthreads();

    if (tid < 128) {
        float s = lb1[tid];
        for (int i = 0; i < 128; i++) s = fmaf(lw1[tid * 128 + i], feat[i], s);
        h1[tid] = fmaxf(s, 0.f);
    }
    __syncthreads();
    if (tid < 64) {
        float s = lb2[tid];
        for (int i = 0; i < 128; i++) s = fmaf(lw2[tid * 128 + i], h1[i], s);
        h2[tid] = fmaxf(s, 0.f);
    }
    __syncthreads();
    if (tid < 5) {
        float s = lb3[tid];
        for (int i = 0; i < 64; i++) s = fmaf(lw3[tid * 64 + i], h2[i], s);
        out[b * 5 + tid] = s;
    }
}

extern "C" void kernel_launch(void* const* d_in, const int* in_sizes, int n_in,
                              void* d_out, int out_size, void* d_ws, size_t ws_size,
                              hipStream_t stream)
{
    const float* x    = (const float*)d_in[0];
    const int*   lens = (const int*)  d_in[1];
    const float* w1 = (const float*)d_in[2];   const float* b1 = (const float*)d_in[3];
    const float* w2 = (const float*)d_in[4];   const float* b2 = (const float*)d_in[5];
    const float* w3 = (const float*)d_in[6];   const float* b3 = (const float*)d_in[7];
    const float* w4 = (const float*)d_in[8];   const float* b4 = (const float*)d_in[9];
    const float* w5 = (const float*)d_in[10];  const float* b5 = (const float*)d_in[11];
    const float* w6 = (const float*)d_in[12];  const float* b6 = (const float*)d_in[13];
    const float* w7 = (const float*)d_in[14];  const float* b7 = (const float*)d_in[15];
    const float* lw1 = (const float*)d_in[16]; const float* lb1 = (const float*)d_in[17];
    const float* lw2 = (const float*)d_in[18]; const float* lb2 = (const float*)d_in[19];
    const float* lw3 = (const float*)d_in[20]; const float* lb3 = (const float*)d_in[21];
    float* out = (float*)d_out;
    char*  W   = (char*)d_ws;

    // lengths: 8192 -> 4092 -> 2044 -> 1020 -> 508 -> 254 -> 125 -> 62 -> 29 -> 14
    size_t off = 0;
    auto take = [&](size_t bytes) {
        size_t o = off; off = (off + bytes + 255) & ~(size_t)255; return o;
    };
    size_t o_y3h = take(((size_t)64 * 96 * 1020 + 2048) * 2);
    size_t o_y4h = take(((size_t)64 * 96 * 254 + 2048) * 2);   // fp16 pooled
    size_t o_y5p = take((size_t)64 * 96 * 62 * 4 + 1024);      // fp32 pooled
    size_t o_y6  = take((size_t)64 * 96 * 29 * 4);
    size_t o_wp1 = take((size_t)79872 * 2);    // 13 steps x 6144
    size_t o_wp2 = take((size_t)110592 * 2);   // 18 steps x 6144
    size_t o_wp3 = take((size_t)110592 * 2);
    size_t o_wp4 = take((size_t)110592 * 2);
    size_t o_wp5 = take((size_t)110592 * 2);
    size_t o_w6r = take((size_t)46080 * 4);
    size_t o_w7r = take((size_t)36864 * 4);
    size_t persist = off;

    auto chunk_bytes = [&](int Bc) -> size_t {
        size_t s = 0;
        s += ((size_t)Bc * 96 * 4092 + 2048) * 2 + 256;
        s += ((size_t)Bc * 96 * 2044 + 2048) * 2 + 256;
        return s;
    };
    int Bc = 64;
    while (Bc > 1 && persist + chunk_bytes(Bc) > ws_size) Bc >>= 1;
    size_t o_y1h = take(((size_t)Bc * 96 * 4092 + 2048) * 2);
    size_t o_y2h = take(((size_t)Bc * 96 * 2044 + 2048) * 2);

    auto US = [&](size_t o) { return (unsigned short*)(W + o); };
    auto FP = [&](size_t o) { return (float*)(W + o); };

    // one repack kernel (605184 elements)
    repack_all<<<dim3((605184 + 255) / 256), 256, 0, stream>>>(
        w1, w2, w3, w4, w5, w6, w7,
        US(o_wp1), US(o_wp2), US(o_wp3), US(o_wp4), US(o_wp5),
        FP(o_w6r), FP(o_w7r));

    const int nchunks = 64 / Bc;
    for (int c = 0; c < nchunks; c++) {
        const float* xc = x + (size_t)c * Bc * 40 * 8192;

        // conv1: v14 config — PIPE=0, KEFF=10, NBLK=256 -> nT=16, LDS 41.8KB
        conv_nb<10, 40, 256, true, true, true, false, 0><<<dim3(Bc * 16), 512, 0, stream>>>(
            (const unsigned short*)xc, US(o_wp1), b1, US(o_y1h), nullptr, 8192, 4092);
        // conv2: PIPE=1 walls, KEFF=6, NBLK=128 -> nT=16, LDS 50.3KB
        conv_nb< 6, 96, 128, false, true, true, false, 1><<<dim3(Bc * 16), 512, 0, stream>>>(
            US(o_y1h), US(o_wp2), b2, US(o_y2h), nullptr, 4092, 2044);
        // conv3: PIPE=1, KEFF=6, NBLK=128 -> nT=8
        unsigned short* y3h_c = US(o_y3h) + (size_t)c * Bc * 96 * 1020;
        conv_nb< 6, 96, 128, false, true, true, false, 1><<<dim3(Bc * 8), 512, 0, stream>>>(
            US(o_y2h), US(o_wp3), b3, y3h_c, nullptr, 2044, 1020);
    }

    // conv4: PIPE=1, NBLK=64 -> nT=8 (grid 512); AvgPool2+ReLU -> y4h (fp16, T=254)
    conv_nb<6, 96, 64, false, false, true, true, 1><<<dim3(64 * 8), 512, 0, stream>>>(
        US(o_y3h), US(o_wp4), b4, US(o_y4h), nullptr, 1020, 508);

    // conv5: PIPE=1, NBLK=64 -> nT=2; AvgPool2+ReLU -> y5p (fp32, T=62)
    conv_nb<6, 96, 64, false, false, false, true, 1><<<dim3(64 * 2), 512, 0, stream>>>(
        US(o_y4h), US(o_wp5), b5, nullptr, FP(o_y5p), 254, 125);

    // conv6: grid 256 (64 samples x 4 o-blocks)
    conv6_k<<<dim3(256), 256, 0, stream>>>(FP(o_y5p), FP(o_w6r), b6, FP(o_y6));

    // conv7 + masked max + MLP head
    tail2<<<dim3(64), 256, 0, stream>>>(
        FP(o_y6), FP(o_w7r), b7, lens, lw1, lb1, lw2, lb2, lw3, lb3, out);
}